// Round 4
// baseline (708.966 us; speedup 1.0000x reference)
//
#include <hip/hip_runtime.h>
#include <hip/hip_bf16.h>

// LSTM cell fused pipeline for MI355X (gfx950).
// B=4096, D=1024, H=2048, O=2048, all f32 in/out; GEMMs run in bf16 MFMA.
//
// Kernels:
//  1. cvt_all:    all f32->bf16 conversions in one grid-stride kernel:
//                 [data|h_prev]->A_cat [B,3072]; [Wi|Wh]->W_cat [8192,3072];
//                 o_prev->o_bf; W_fb->Wfb_bf; W_out->Wout_bf
//  2. gemm_bt<0>: C = A[M,K] * W[N,K]^T + bias  (f32 out)   -- fb and logits
//  3. gemm_bt<1>: gates GEMM with fused LSTM epilogue (c_t, h_t, h_bf16)
//  4. softmax:    row softmax of logits -> d_out
//
// GEMM structure = m97 ladder step 3 (HW-verified 874-912 TF @4096^3):
// 128x128 tile, BK=64, 4 waves (2x2), single-buffered LDS,
// global_load_lds width 16, 16x16x32 bf16 MFMA, acc[4][4]/wave,
// XCD-aware bijective block swizzle.

#define DEV __device__ __forceinline__

typedef __bf16 bf16x8 __attribute__((ext_vector_type(8)));
typedef float  f32x4  __attribute__((ext_vector_type(4)));

static_assert(sizeof(bf16x8) == 16, "bf16x8 must be 16B");

DEV unsigned short f2bf(float f) {  // RTNE f32->bf16 (finite inputs)
  union { float f; unsigned u; } x; x.f = f;
  unsigned r = x.u + 0x7fffu + ((x.u >> 16) & 1u);
  return (unsigned short)(r >> 16);
}

DEV float sigm(float x) { return 1.f / (1.f + __expf(-x)); }

DEV void gload_lds16(const void* g, void* l) {
  // async global->LDS, 16B per lane; LDS dest is wave-uniform base + lane*16
  __builtin_amdgcn_global_load_lds(
      (__attribute__((address_space(1))) void*)(void*)g,
      (__attribute__((address_space(3))) void*)l, 16, 0, 0);
}

// ---------------- fused conversion kernel ----------------
// Processes 4 f32 -> 4 bf16 per work item, grid-stride over 5 regions.

struct CvtArgs {
  const float *data, *h_prev, *Wi, *Wh, *o_prev, *W_fb, *W_out;
  unsigned short *A_cat, *W_cat, *o_bf, *Wfb_bf, *Wout_bf;
};

DEV void cvt4(const float* src, unsigned short* dst) {
  float4 v = *reinterpret_cast<const float4*>(src);
  ushort4 o;
  o.x = f2bf(v.x); o.y = f2bf(v.y); o.z = f2bf(v.z); o.w = f2bf(v.w);
  *reinterpret_cast<ushort4*>(dst) = o;
}

__global__ __launch_bounds__(256)
void cvt_all_kernel(CvtArgs a) {
  // region boundaries in 4-element groups
  const long t0 = 4096L * 3072 / 4;            // A_cat
  const long t1 = t0 + 8192L * 3072 / 4;       // W_cat
  const long t2 = t1 + 4096L * 2048 / 4;       // o_bf
  const long t3 = t2 + 2048L * 2048 / 4;       // Wfb_bf
  const long t4 = t3 + 2048L * 2048 / 4;       // Wout_bf
  long stride = (long)gridDim.x * blockDim.x;
  for (long g = (long)blockIdx.x * blockDim.x + threadIdx.x; g < t4; g += stride) {
    if (g < t0) {               // A_cat = [data | h_prev], rows of 3072
      long e = g << 2;
      int col = (int)(e % 3072);
      long row = e / 3072;
      const float* src = (col < 1024) ? (a.data + row * 1024 + col)
                                      : (a.h_prev + row * 2048 + (col - 1024));
      cvt4(src, a.A_cat + e);
    } else if (g < t1) {        // W_cat = [Wi | Wh], rows of 3072
      long e = (g - t0) << 2;
      int col = (int)(e % 3072);
      long row = e / 3072;
      const float* src = (col < 1024) ? (a.Wi + row * 1024 + col)
                                      : (a.Wh + row * 2048 + (col - 1024));
      cvt4(src, a.W_cat + e);
    } else if (g < t2) {
      long e = (g - t1) << 2;
      cvt4(a.o_prev + e, a.o_bf + e);
    } else if (g < t3) {
      long e = (g - t2) << 2;
      cvt4(a.W_fb + e, a.Wfb_bf + e);
    } else {
      long e = (g - t3) << 2;
      cvt4(a.W_out + e, a.Wout_bf + e);
    }
  }
}

// ---------------- GEMM ----------------
// MODE 0: out[m,n] = sum_k A[m,k]*W[n,k] + bias[n]
// MODE 1: gates GEMM, N=8192 logical; B-tile local row lr = wc*64 + g*16 + r
//         maps to W row g*2048 + bn*32 + wc*16 + r, so each wave's 4 col
//         fragments are gates (i,f,g,o) of the same h = bn*32 + wc*16 + (l&15).
//         Fused epilogue computes c_t, h_t; writes out_c/out_h (f32) + h_bf.

template<int MODE>
__global__ __launch_bounds__(256, 2)
void gemm_bt(const unsigned short* __restrict__ A,   // [M,K] bf16
             const unsigned short* __restrict__ W,   // [N,K] bf16
             const float* __restrict__ bias,
             float* __restrict__ out,
             const float* __restrict__ c_prev,
             const float* __restrict__ fb,
             float* __restrict__ out_h,
             float* __restrict__ out_c,
             unsigned short* __restrict__ h_bf,
             int M, int N, int K, int ntn) {
  __shared__ unsigned short As[128 * 64];
  __shared__ unsigned short Bs[128 * 64];

  int nwg = gridDim.x;
  int wg = blockIdx.x;
  if ((nwg & 7) == 0) {                // XCD-aware swizzle (bijective: nwg%8==0)
    int q = nwg >> 3;
    wg = (wg & 7) * q + (wg >> 3);
  }
  int bm = wg / ntn, bn = wg % ntn;
  int m0 = bm * 128;

  int tid = threadIdx.x;
  int w = tid >> 6, l = tid & 63;
  int wr = w >> 1, wc = w & 1;

  // staging: 16 chunks of 1KB per matrix; wave w owns chunks 4w..4w+3.
  // chunk c = rows c*8..c*8+7 (128B/row); lane l -> row c*8+(l>>3), k=(l&7)*8
  size_t goffA[4], goffB[4];
#pragma unroll
  for (int j = 0; j < 4; ++j) {
    int c = w * 4 + j;
    int lr = c * 8 + (l >> 3);
    int kk = (l & 7) * 8;
    goffA[j] = (size_t)(m0 + lr) * K + kk;
    int grow;
    if (MODE == 0) {
      grow = bn * 128 + lr;
    } else {
      grow = ((lr >> 4) & 3) * 2048 + bn * 32 + ((lr >> 6) << 4) + (lr & 15);
    }
    goffB[j] = (size_t)grow * K + kk;
  }

  f32x4 acc[4][4];
#pragma unroll
  for (int i = 0; i < 4; ++i)
#pragma unroll
    for (int j = 0; j < 4; ++j) acc[i][j] = (f32x4){0.f, 0.f, 0.f, 0.f};

  int arow = wr * 64 + (l & 15);
  int brow = wc * 64 + (l & 15);
  int kfrag = (l >> 4) * 8;

  for (int k0 = 0; k0 < K; k0 += 64) {
#pragma unroll
    for (int j = 0; j < 4; ++j) {
      gload_lds16(A + goffA[j] + k0, &As[(w * 4 + j) * 512]);
      gload_lds16(W + goffB[j] + k0, &Bs[(w * 4 + j) * 512]);
    }
    __syncthreads();   // compiler drains vmcnt before s_barrier
#pragma unroll
    for (int ks = 0; ks < 2; ++ks) {
      bf16x8 a[4], b[4];
#pragma unroll
      for (int mi = 0; mi < 4; ++mi)
        a[mi] = *reinterpret_cast<const bf16x8*>(&As[(arow + mi * 16) * 64 + ks * 32 + kfrag]);
#pragma unroll
      for (int ni = 0; ni < 4; ++ni)
        b[ni] = *reinterpret_cast<const bf16x8*>(&Bs[(brow + ni * 16) * 64 + ks * 32 + kfrag]);
#pragma unroll
      for (int mi = 0; mi < 4; ++mi)
#pragma unroll
        for (int ni = 0; ni < 4; ++ni)
          acc[mi][ni] = __builtin_amdgcn_mfma_f32_16x16x32_bf16(a[mi], b[ni], acc[mi][ni], 0, 0, 0);
    }
    __syncthreads();   // all waves done reading before next stage overwrites
  }

  if (MODE == 0) {
#pragma unroll
    for (int mi = 0; mi < 4; ++mi) {
#pragma unroll
      for (int r = 0; r < 4; ++r) {
        int m = m0 + wr * 64 + mi * 16 + ((l >> 4) << 2) + r;
#pragma unroll
        for (int ni = 0; ni < 4; ++ni) {
          int n = bn * 128 + wc * 64 + ni * 16 + (l & 15);
          out[(size_t)m * N + n] = acc[mi][ni][r] + bias[n];
        }
      }
    }
  } else {
    int h = bn * 32 + wc * 16 + (l & 15);
    float bii = bias[h], bif = bias[2048 + h], big = bias[4096 + h], bio = bias[6144 + h];
#pragma unroll
    for (int mi = 0; mi < 4; ++mi) {
#pragma unroll
      for (int r = 0; r < 4; ++r) {
        int m = m0 + wr * 64 + mi * 16 + ((l >> 4) << 2) + r;
        size_t idx = (size_t)m * 2048 + h;
        float iv = sigm(acc[mi][0][r] + bii);
        float fv = sigm(acc[mi][1][r] + bif);
        float gv = tanhf(acc[mi][2][r] + big);
        float ov = sigm(acc[mi][3][r] + bio);
        float c = fv * c_prev[idx] + iv * gv + fb[idx];
        float ht = ov * tanhf(c);
        out_c[idx] = c;
        out_h[idx] = ht;
        h_bf[idx] = f2bf(ht);
      }
    }
  }
}

// ---------------- softmax ----------------

__global__ __launch_bounds__(256)
void softmax_kernel(const float* __restrict__ logits, float* __restrict__ out) {
  int row = blockIdx.x;
  int tid = threadIdx.x;
  const float* x = logits + (size_t)row * 2048;
  float4 v0 = *reinterpret_cast<const float4*>(x + tid * 4);
  float4 v1 = *reinterpret_cast<const float4*>(x + 1024 + tid * 4);
  float mx = fmaxf(fmaxf(fmaxf(v0.x, v0.y), fmaxf(v0.z, v0.w)),
                   fmaxf(fmaxf(v1.x, v1.y), fmaxf(v1.z, v1.w)));
#pragma unroll
  for (int o = 32; o; o >>= 1) mx = fmaxf(mx, __shfl_xor(mx, o));
  __shared__ float redm[4], reds[4];
  int w = tid >> 6, l = tid & 63;
  if (l == 0) redm[w] = mx;
  __syncthreads();
  mx = fmaxf(fmaxf(redm[0], redm[1]), fmaxf(redm[2], redm[3]));
  float e[8];
  e[0] = __expf(v0.x - mx); e[1] = __expf(v0.y - mx);
  e[2] = __expf(v0.z - mx); e[3] = __expf(v0.w - mx);
  e[4] = __expf(v1.x - mx); e[5] = __expf(v1.y - mx);
  e[6] = __expf(v1.z - mx); e[7] = __expf(v1.w - mx);
  float s = ((e[0] + e[1]) + (e[2] + e[3])) + ((e[4] + e[5]) + (e[6] + e[7]));
#pragma unroll
  for (int o = 32; o; o >>= 1) s += __shfl_xor(s, o);
  if (l == 0) reds[w] = s;
  __syncthreads();
  s = reds[0] + reds[1] + reds[2] + reds[3];
  float inv = 1.f / s;
  float4 o0, o1;
  o0.x = e[0] * inv; o0.y = e[1] * inv; o0.z = e[2] * inv; o0.w = e[3] * inv;
  o1.x = e[4] * inv; o1.y = e[5] * inv; o1.z = e[6] * inv; o1.w = e[7] * inv;
  float* y = out + (size_t)row * 2048;
  *reinterpret_cast<float4*>(y + tid * 4) = o0;
  *reinterpret_cast<float4*>(y + 1024 + tid * 4) = o1;
}

// ---------------- launch ----------------

extern "C" void kernel_launch(void* const* d_in, const int* in_sizes, int n_in,
                              void* d_out, int out_size, void* d_ws, size_t ws_size,
                              hipStream_t stream) {
  const float* data   = (const float*)d_in[0];
  const float* h_prev = (const float*)d_in[1];
  const float* c_prev = (const float*)d_in[2];
  const float* o_prev = (const float*)d_in[3];
  const float* Wi     = (const float*)d_in[4];
  const float* bi     = (const float*)d_in[5];
  const float* Wh     = (const float*)d_in[6];
  const float* W_out  = (const float*)d_in[7];
  const float* b_out  = (const float*)d_in[8];
  const float* W_fb   = (const float*)d_in[9];
  const float* b_fb   = (const float*)d_in[10];

  constexpr int B = 4096, H = 2048, O = 2048;
  constexpr size_t BH = (size_t)B * H;

  char* ws = (char*)d_ws;
  unsigned short* A_cat  = (unsigned short*)ws; ws += (size_t)B * 3072 * 2;      // 25.2 MB
  unsigned short* W_cat  = (unsigned short*)ws; ws += (size_t)4 * H * 3072 * 2;  // 50.3 MB
  unsigned short* o_bf   = (unsigned short*)ws; ws += BH * 2;                    // 16.8 MB
  unsigned short* Wfb_bf = (unsigned short*)ws; ws += (size_t)H * H * 2;         //  8.4 MB
  unsigned short* Wout_bf= (unsigned short*)ws; ws += (size_t)O * H * 2;         //  8.4 MB
  float*          fb_f   = (float*)ws;          ws += BH * 4;                    // 33.6 MB (reused for logits)
  // h_bf ALIASES o_bf: fb GEMM's reads of o_bf complete (stream order) before
  // the gates GEMM writes h_bf. Saves 16.8 MB of ws.
  unsigned short* h_bf   = o_bf;
  // total ~142.6 MB of ws

  float* out_p = (float*)d_out;            // softmax output [B,O]
  float* out_h = out_p + (size_t)B * O;    // h_t [B,H]
  float* out_c = out_h + BH;               // c_t [B,H]

  CvtArgs ca;
  ca.data = data; ca.h_prev = h_prev; ca.Wi = Wi; ca.Wh = Wh;
  ca.o_prev = o_prev; ca.W_fb = W_fb; ca.W_out = W_out;
  ca.A_cat = A_cat; ca.W_cat = W_cat; ca.o_bf = o_bf;
  ca.Wfb_bf = Wfb_bf; ca.Wout_bf = Wout_bf;
  cvt_all_kernel<<<2048, 256, 0, stream>>>(ca);

  // fb = o_prev @ W_fb^T + b_fb
  gemm_bt<0><<<(B / 128) * (H / 128), 256, 0, stream>>>(
      o_bf, Wfb_bf, b_fb, fb_f, nullptr, nullptr, nullptr, nullptr, nullptr,
      B, H, H, H / 128);
  // gates (fused LSTM epilogue)
  gemm_bt<1><<<(B / 128) * (4 * H / 128), 256, 0, stream>>>(
      A_cat, W_cat, bi, nullptr, c_prev, fb_f, out_h, out_c, h_bf,
      B, 4 * H, 3072, (4 * H) / 128);
  // logits = h_t @ W_out^T + b_out  (into fb_f, no longer needed)
  gemm_bt<0><<<(B / 128) * (O / 128), 256, 0, stream>>>(
      h_bf, Wout_bf, b_out, fb_f, nullptr, nullptr, nullptr, nullptr, nullptr,
      B, O, H, O / 128);
  softmax_kernel<<<B, 256, 0, stream>>>(fb_f, out_p);
}